// Round 1
// baseline (1135.547 us; speedup 1.0000x reference)
//
#include <hip/hip_runtime.h>
#include <hip/hip_bf16.h>

typedef __hip_bfloat16 bf16;
typedef unsigned short u16;
typedef unsigned char u8;
typedef unsigned int u32;
typedef __attribute__((ext_vector_type(8))) unsigned short us8;

static __device__ __forceinline__ float b2f(bf16 v) { return __bfloat162float(v); }
static __device__ __forceinline__ float bfu2f(u16 u) {
    union { u32 i; float f; } c; c.i = ((u32)u) << 16; return c.f;
}
static __device__ __forceinline__ u16 f2bfu(float f) {
    u32 x = __float_as_uint(f);
    return (u16)((x + 0x7FFFu + ((x >> 16) & 1u)) >> 16);
}

#define TILE 4096        // edges per partition block (LDS staging)
#define RPT16(M) M(0) M(1) M(2) M(3) M(4) M(5) M(6) M(7) \
                 M(8) M(9) M(10) M(11) M(12) M(13) M(14) M(15)

struct SP {
    const int* src; const int* dst;
    int E, N, bits, cap;
    int* gcur; u32* pairs;
    int* rowptr; float* dis; int* csr;
};
struct Pack {
    SP s[4];
    int poff[4];  // partition-grid start offset per stage
    int boff[4];  // build-grid start offset per stage
};

// ---------------- dtype detection ----------------
__global__ void k_detect(const u16* __restrict__ xraw, int* __restrict__ flag) {
    __shared__ int s;
    if (threadIdx.x == 0) s = 0;
    __syncthreads();
    u16 u = xraw[threadIdx.x];
    int e = (u >> 7) & 0xFF;
    if (e >= 0x8F) atomicAdd(&s, 1);
    __syncthreads();
    if (threadIdx.x == 0) flag[0] = (s > 0) ? 1 : 0;
}

// zero all 4 gcursor blocks + write rowptr sentinels
__global__ void k_init(int* __restrict__ gcur_all, Pack pk) {
    int i = blockIdx.x * blockDim.x + threadIdx.x;
    if (i < 2048) gcur_all[i] = 0;
    if (i < 4) pk.s[i].rowptr[pk.s[i].N] = pk.s[i].E;
}

// ---------------- fused pass A: all 4 stages' partitions ----------------
// pairs[bucket*cap + slot] = (bucket_local_dst << 20) | src   (src < 2^20)
__global__ void k_partition4(Pack pk) {
    __shared__ u32 stage[TILE];   // 16 KB
    __shared__ u8  bkt[TILE];     //  4 KB
    __shared__ int hist[256];
    __shared__ int lofs[256];
    __shared__ int gbase[256];
    __shared__ int lcur[256];
    __shared__ int tmp[256];

    int bid = blockIdx.x;
    int si = (bid >= pk.poff[3]) ? 3 : (bid >= pk.poff[2]) ? 2 : (bid >= pk.poff[1]) ? 1 : 0;
    const SP sp = pk.s[si];
    int lb = bid - pk.poff[si];

    int t = threadIdx.x;
    int e0 = lb * TILE;
    int n = min(TILE, sp.E - e0);
    int bits = sp.bits;
    const int* dstp = sp.dst + e0;
    const int* srcp = sp.src + e0;

#define LOADK(k) int d##k, s##k; { int i = t + 256*(k); \
    if (i < n) { d##k = dstp[i]; s##k = srcp[i]; } else { d##k = -1; s##k = 0; } }
    RPT16(LOADK)
#undef LOADK

    hist[t] = 0;
    __syncthreads();
#define HISTK(k) if (d##k >= 0) atomicAdd(&hist[d##k >> bits], 1);
    RPT16(HISTK)
#undef HISTK
    __syncthreads();

    int h = hist[t];
    tmp[t] = h; __syncthreads();
    for (int off = 1; off < 256; off <<= 1) {
        int v = (t >= off) ? tmp[t - off] : 0;
        __syncthreads();
        tmp[t] += v;
        __syncthreads();
    }
    lofs[t] = tmp[t] - h;
    gbase[t] = h ? atomicAdd(&sp.gcur[t], h) : 0;
    lcur[t] = tmp[t] - h;
    __syncthreads();

    u32 mask = (1u << bits) - 1u;
#define SCATK(k) if (d##k >= 0) { int b = d##k >> bits; \
    int pos = atomicAdd(&lcur[b], 1); \
    stage[pos] = (((u32)d##k & mask) << 20) | (u32)s##k; \
    bkt[pos] = (u8)b; }
    RPT16(SCATK)
#undef SCATK
    __syncthreads();

    int cap = sp.cap;
    u32* pairs = sp.pairs;
    for (int i = t; i < n; i += 256) {
        int b = bkt[i];
        pairs[(size_t)b * cap + gbase[b] + (i - lofs[b])] = stage[i];
    }
}

// ---------------- fused pass B: all 4 stages' builds ----------------
// csr now stores the PACKED word (local_dst<<20 | src); consumers mask.
__global__ void k_build4(Pack pk) {
    __shared__ int hist[4096];   // 16 KB
    __shared__ int ofs[4096];    // 16 KB
    __shared__ int tmp[256];
    __shared__ int bscan[256];

    int bid = blockIdx.x;
    int si = (bid >= pk.boff[3]) ? 3 : (bid >= pk.boff[2]) ? 2 : (bid >= pk.boff[1]) ? 1 : 0;
    const SP sp = pk.s[si];
    int b = bid - pk.boff[si];
    int t = threadIdx.x;
    int bits = sp.bits;
    int range = 1 << bits;

    {
        int v = sp.gcur[t];
        tmp[t] = v; __syncthreads();
        for (int off = 1; off < 256; off <<= 1) {
            int w = (t >= off) ? tmp[t - off] : 0;
            __syncthreads();
            tmp[t] += w;
            __syncthreads();
        }
        bscan[t] = tmp[t] - v;
        __syncthreads();
    }
    int bbase = bscan[b];
    int tot = sp.gcur[b];

    for (int i = t; i < range; i += 256) hist[i] = 0;
    __syncthreads();
    const u32* p = sp.pairs + (size_t)b * sp.cap;
    for (int i = t; i < tot; i += 256)
        atomicAdd(&hist[p[i] >> 20], 1);
    __syncthreads();

    int bpt = range >> 8;  // bins per thread
    int lbase = t * bpt;
    int s = 0;
    for (int k = 0; k < bpt; k++) s += hist[lbase + k];
    tmp[t] = s; __syncthreads();
    for (int off = 1; off < 256; off <<= 1) {
        int v = (t >= off) ? tmp[t - off] : 0;
        __syncthreads();
        tmp[t] += v;
        __syncthreads();
    }
    int run = tmp[t] - s;
    for (int k = 0; k < bpt; k++) { ofs[lbase + k] = run; run += hist[lbase + k]; }
    __syncthreads();

    int nbase = b << bits;
    for (int i = t; i < range; i += 256) {
        int v = nbase + i;
        if (v < sp.N) {
            sp.rowptr[v] = bbase + ofs[i];
            sp.dis[v] = rsqrtf((float)(hist[i] + 1));
        }
    }
    for (int i = t; i < range; i += 256) hist[i] = ofs[i];  // reuse as cursor
    __syncthreads();
    for (int i = t; i < tot; i += 256) {
        u32 u = p[i];
        int pos = atomicAdd(&hist[u >> 20], 1);
        sp.csr[bbase + pos] = (int)u;   // keep packed (local_dst<<20 | src)
    }
}

// ---------------- pre-scale: g[v,f] = dis[v] * x_in[row(v), f] ----------------
template <int F, bool EXT>
__global__ void k_pre(const void* __restrict__ xin, const int* __restrict__ gidx,
                      const bf16* __restrict__ actin, const float* __restrict__ dis,
                      bf16* __restrict__ g, const int* __restrict__ flag, int total) {
    int i = blockIdx.x * blockDim.x + threadIdx.x;
    if (i >= total) return;
    int v = i / F;
    int f = i - v * F;
    float x;
    if (EXT) {
        if (flag[0]) x = ((const float*)xin)[i];
        else         x = b2f(((const bf16*)xin)[i]);
    } else {
        int row = gidx[v];
        x = b2f(actin[(size_t)row * F + f]);
    }
    g[i] = __float2bfloat16(dis[v] * x);
}

// ---------------- W-first matmul: g[v,:] = bf16(dis[v] * (act[gidx(v)] @ W)) ----------------
template <int FIN, int FOUT>
__global__ void k_matmul(const int* __restrict__ gidx, const bf16* __restrict__ actin,
                         const void* __restrict__ W, const float* __restrict__ dis,
                         bf16* __restrict__ g, const int* __restrict__ flag, int n) {
    __shared__ float Ws[FIN * FOUT];
    const int f32m = flag[0];
    for (int i = threadIdx.x; i < FIN * FOUT; i += blockDim.x)
        Ws[i] = f32m ? ((const float*)W)[i] : b2f(((const bf16*)W)[i]);
    __syncthreads();
    int v = blockIdx.x * blockDim.x + threadIdx.x;
    if (v >= n) return;
    int row = gidx[v];
    float x[FIN];
    if constexpr (FIN % 8 == 0) {
        #pragma unroll
        for (int k8 = 0; k8 < FIN / 8; k8++) {
            us8 xv = *(const us8*)(actin + (size_t)row * FIN + k8 * 8);
            #pragma unroll
            for (int j = 0; j < 8; j++) x[k8 * 8 + j] = bfu2f(xv[j]);
        }
    } else {
        #pragma unroll
        for (int k = 0; k < FIN; k++) x[k] = b2f(actin[(size_t)row * FIN + k]);
    }
    float y[FOUT];
    #pragma unroll
    for (int f = 0; f < FOUT; f++) y[f] = 0.f;
    #pragma unroll
    for (int k = 0; k < FIN; k++) {
        float xk = x[k];
        #pragma unroll
        for (int f = 0; f < FOUT; f++) y[f] = fmaf(xk, Ws[k * FOUT + f], y[f]);
    }
    float dv = dis[v];
    if constexpr (FOUT % 8 == 0) {
        #pragma unroll
        for (int f8 = 0; f8 < FOUT / 8; f8++) {
            us8 ov;
            #pragma unroll
            for (int j = 0; j < 8; j++) ov[j] = f2bfu(dv * y[f8 * 8 + j]);
            *(us8*)(g + (size_t)v * FOUT + f8 * 8) = ov;
        }
    } else {
        #pragma unroll
        for (int f = 0; f < FOUT; f++)
            g[(size_t)v * FOUT + f] = __float2bfloat16(dv * y[f]);
    }
}

// ---------------- post matmul (agg-first): act = relu(xt @ W + b) ----------------
template <int FIN, int FOUT>
__global__ void k_matmul_post(const bf16* __restrict__ xt, const void* __restrict__ W,
                              const void* __restrict__ bias, bf16* __restrict__ act,
                              const int* __restrict__ flag, int n) {
    __shared__ float Ws[FIN * FOUT];
    __shared__ float Bs[FOUT];
    const int f32m = flag[0];
    for (int i = threadIdx.x; i < FIN * FOUT; i += blockDim.x)
        Ws[i] = f32m ? ((const float*)W)[i] : b2f(((const bf16*)W)[i]);
    for (int i = threadIdx.x; i < FOUT; i += blockDim.x)
        Bs[i] = f32m ? ((const float*)bias)[i] : b2f(((const bf16*)bias)[i]);
    __syncthreads();
    int v = blockIdx.x * blockDim.x + threadIdx.x;
    if (v >= n) return;
    float x[FIN];
    if constexpr (FIN % 8 == 0) {
        #pragma unroll
        for (int k8 = 0; k8 < FIN / 8; k8++) {
            us8 xv = *(const us8*)(xt + (size_t)v * FIN + k8 * 8);
            #pragma unroll
            for (int j = 0; j < 8; j++) x[k8 * 8 + j] = bfu2f(xv[j]);
        }
    } else {
        #pragma unroll
        for (int k = 0; k < FIN; k++) x[k] = b2f(xt[(size_t)v * FIN + k]);
    }
    float y[FOUT];
    #pragma unroll
    for (int f = 0; f < FOUT; f++) y[f] = Bs[f];
    #pragma unroll
    for (int k = 0; k < FIN; k++) {
        float xk = x[k];
        #pragma unroll
        for (int f = 0; f < FOUT; f++) y[f] = fmaf(xk, Ws[k * FOUT + f], y[f]);
    }
    if constexpr (FOUT % 8 == 0) {
        #pragma unroll
        for (int f8 = 0; f8 < FOUT / 8; f8++) {
            us8 ov;
            #pragma unroll
            for (int j = 0; j < 8; j++) {
                float val = y[f8 * 8 + j];
                ov[j] = f2bfu(val > 0.f ? val : 0.f);
            }
            *(us8*)(act + (size_t)v * FOUT + f8 * 8) = ov;
        }
    } else {
        #pragma unroll
        for (int f = 0; f < FOUT; f++)
            act[(size_t)v * FOUT + f] = __float2bfloat16(y[f] > 0.f ? y[f] : 0.f);
    }
}

// ---------------- edge-parallel gather, FOUT=32, LDS f32 accumulate ----------------
// Block owns 64 dst vertices. csr words carry (local_dst<<20|src); local_dst&63
// equals v-v0 because buckets (>=512) and v0 (64-aligned) nest.
// 4 lanes per edge, each lane loads ushort8 (16B) -> one 64B line per edge.
template <bool FINALIZE>
__global__ void __launch_bounds__(256) k_gather32e(
        const bf16* __restrict__ g, const int* __restrict__ rowptr,
        const int* __restrict__ csr, const float* __restrict__ dis,
        const void* __restrict__ bias, bf16* __restrict__ out,
        const int* __restrict__ flag, int N) {
    __shared__ float acc[64][33];   // +1 pad: random-dl ds_add spreads banks
    __shared__ int csr_s[1024];
    __shared__ float Bs[32];

    int t = threadIdx.x;
    int v0 = blockIdx.x << 6;
    int nv = min(64, N - v0);

    for (int i = t; i < 64 * 33; i += 256) ((float*)acc)[i] = 0.f;
    if (FINALIZE && t < 32)
        Bs[t] = flag[0] ? ((const float*)bias)[t] : b2f(((const bf16*)bias)[t]);

    int R0 = rowptr[v0];
    int R1 = rowptr[v0 + nv];
    int fg = t & 3;        // 8-feature group
    int es = t >> 2;       // edge slot 0..63

    for (int base = R0; base < R1; base += 1024) {
        int n = min(1024, R1 - base);
        __syncthreads();
        for (int i = t; i < n; i += 256) csr_s[i] = csr[base + i];
        __syncthreads();
        #pragma unroll 2
        for (int i = es; i < n; i += 64) {
            u32 u = (u32)csr_s[i];
            int src = (int)(u & 0xFFFFFu);
            int dl = (int)((u >> 20) & 63u);
            us8 val = *(const us8*)(g + ((size_t)src << 5) + (fg << 3));
            float* a = &acc[dl][fg << 3];
            atomicAdd(&a[0], bfu2f(val[0]));
            atomicAdd(&a[1], bfu2f(val[1]));
            atomicAdd(&a[2], bfu2f(val[2]));
            atomicAdd(&a[3], bfu2f(val[3]));
            atomicAdd(&a[4], bfu2f(val[4]));
            atomicAdd(&a[5], bfu2f(val[5]));
            atomicAdd(&a[6], bfu2f(val[6]));
            atomicAdd(&a[7], bfu2f(val[7]));
        }
    }
    __syncthreads();

    int vl = t >> 2;
    if (vl < nv) {
        int v = v0 + vl;
        float dv = dis[v];
        us8 sv = *(const us8*)(g + ((size_t)v << 5) + (fg << 3));
        us8 ov;
        #pragma unroll
        for (int k = 0; k < 8; k++) {
            float s = acc[vl][(fg << 3) + k] + bfu2f(sv[k]);
            float val;
            if (FINALIZE) {
                val = fmaf(dv, s, Bs[(fg << 3) + k]);
                val = val > 0.f ? val : 0.f;
            } else {
                val = dv * s;
            }
            ov[k] = f2bfu(val);
        }
        *(us8*)(out + ((size_t)v << 5) + (fg << 3)) = ov;
    }
}

// ---------------- edge-parallel gather, FOUT=3 ----------------
// Block owns 256 dst vertices; one edge per thread per step.
template <bool FINALIZE>
__global__ void __launch_bounds__(256) k_gather3e(
        const bf16* __restrict__ g, const int* __restrict__ rowptr,
        const int* __restrict__ csr, const float* __restrict__ dis,
        const void* __restrict__ bias, bf16* __restrict__ out,
        const int* __restrict__ flag, int N) {
    __shared__ float acc[256 * 5];   // stride 5 (coprime 32) spreads banks
    __shared__ int csr_s[1024];
    __shared__ float Bs[3];

    int t = threadIdx.x;
    int v0 = blockIdx.x << 8;
    int nv = min(256, N - v0);

    for (int i = t; i < 256 * 5; i += 256) acc[i] = 0.f;
    if (FINALIZE && t < 3)
        Bs[t] = flag[0] ? ((const float*)bias)[t] : b2f(((const bf16*)bias)[t]);

    int R0 = rowptr[v0];
    int R1 = rowptr[v0 + nv];
    const u16* g16 = (const u16*)g;

    for (int base = R0; base < R1; base += 1024) {
        int n = min(1024, R1 - base);
        __syncthreads();
        for (int i = t; i < n; i += 256) csr_s[i] = csr[base + i];
        __syncthreads();
        #pragma unroll 2
        for (int i = t; i < n; i += 256) {
            u32 u = (u32)csr_s[i];
            int src = (int)(u & 0xFFFFFu);
            int dl = (int)((u >> 20) & 255u);
            size_t b = (size_t)src * 3;
            float a0 = bfu2f(g16[b]);
            float a1 = bfu2f(g16[b + 1]);
            float a2 = bfu2f(g16[b + 2]);
            atomicAdd(&acc[dl * 5 + 0], a0);
            atomicAdd(&acc[dl * 5 + 1], a1);
            atomicAdd(&acc[dl * 5 + 2], a2);
        }
    }
    __syncthreads();

    if (t < nv) {
        int v = v0 + t;
        float dv = dis[v];
        size_t b = (size_t)v * 3;
        u16* o16 = (u16*)out;
        #pragma unroll
        for (int k = 0; k < 3; k++) {
            float s = acc[t * 5 + k] + bfu2f(g16[b + k]);
            float val;
            if (FINALIZE) {
                val = fmaf(dv, s, Bs[k]);
                val = val > 0.f ? val : 0.f;
            } else {
                val = dv * s;
            }
            o16[b + k] = f2bfu(val);
        }
    }
}

// ---------------- final unpool gather -> out (dtype per flag) ----------------
__global__ void k_gather_out(const bf16* __restrict__ act, const int* __restrict__ idx,
                             void* __restrict__ out, const int* __restrict__ flag, int n) {
    int u = blockIdx.x * blockDim.x + threadIdx.x;
    if (u >= n) return;
    size_t r = (size_t)idx[u];
    float v0 = b2f(act[3 * r + 0]);
    float v1 = b2f(act[3 * r + 1]);
    float v2 = b2f(act[3 * r + 2]);
    if (flag[0]) {
        float* o = (float*)out;
        o[3 * (size_t)u + 0] = v0; o[3 * (size_t)u + 1] = v1; o[3 * (size_t)u + 2] = v2;
    } else {
        bf16* o = (bf16*)out;
        o[3 * (size_t)u + 0] = __float2bfloat16(v0);
        o[3 * (size_t)u + 1] = __float2bfloat16(v1);
        o[3 * (size_t)u + 2] = __float2bfloat16(v2);
    }
}

static inline int cdiv(long long a, long long b) { return (int)((a + b - 1) / b); }

static inline int range_bits_for(int N) {
    int bits = 8;
    while (cdiv(N, 1 << bits) > 256) bits++;
    return bits;
}

extern "C" void kernel_launch(void* const* d_in, const int* in_sizes, int n_in,
                              void* d_out, int out_size, void* d_ws, size_t ws_size,
                              hipStream_t stream) {
    const void* x  = d_in[0];
    const void* W1 = d_in[1]; const void* b1 = d_in[2];
    const void* W2 = d_in[3]; const void* b2 = d_in[4];
    const void* W3 = d_in[5]; const void* b3 = d_in[6];
    const void* W4 = d_in[7]; const void* b4 = d_in[8];
    const int* e0  = (const int*)d_in[9];
    const int* up1 = (const int*)d_in[10];
    const int* e1  = (const int*)d_in[11];
    const int* up2 = (const int*)d_in[12];
    const int* e2  = (const int*)d_in[13];
    const int* up3 = (const int*)d_in[14];
    const int* e3  = (const int*)d_in[15];
    const int* up4 = (const int*)d_in[16];

    const int N0 = in_sizes[0] / 3;
    const int N1 = in_sizes[10];
    const int N2 = in_sizes[12];
    const int N3 = in_sizes[14];
    const int N4 = in_sizes[16];
    const int E0 = in_sizes[9] / 2, E1 = in_sizes[11] / 2;
    const int E2 = in_sizes[13] / 2, E3 = in_sizes[15] / 2;

    int Ns[4] = {N0, N1, N2, N3};
    int Es[4] = {E0, E1, E2, E3};
    const int* srcs[4] = {e0, e1, e2, e3};
    const int* dsts[4] = {e0 + E0, e1 + E1, e2 + E2, e3 + E3};

    // buffer element counts
    size_t gmax = (size_t)N0 * 3;
    if ((size_t)N1 * 32 > gmax) gmax = (size_t)N1 * 32;
    if ((size_t)N2 * 32 > gmax) gmax = (size_t)N2 * 32;
    if ((size_t)N3 * 3  > gmax) gmax = (size_t)N3 * 3;
    size_t amax = (size_t)N0 * 32;
    if ((size_t)N1 * 64 > amax) amax = (size_t)N1 * 64;
    if ((size_t)N2 * 32 > amax) amax = (size_t)N2 * 32;
    if ((size_t)N3 * 3  > amax) amax = (size_t)N3 * 3;
    size_t xmax = (size_t)N0 * 3;
    if ((size_t)N1 * 32 > xmax) xmax = (size_t)N1 * 32;
    gmax = (gmax + 7) & ~(size_t)7;
    amax = (amax + 7) & ~(size_t)7;
    xmax = (xmax + 7) & ~(size_t)7;

    Pack pk;
    char* p = (char*)d_ws;
    int* flag = (int*)p;            p += 256;
    int* gcur_all = (int*)p;        p += 2048 * 4;

    for (int s = 0; s < 4; s++) {
        pk.s[s].src = srcs[s]; pk.s[s].dst = dsts[s];
        pk.s[s].E = Es[s]; pk.s[s].N = Ns[s];
        pk.s[s].bits = range_bits_for(Ns[s]);
        int nb = cdiv(Ns[s], 1 << pk.s[s].bits);
        pk.s[s].cap = Es[s] / nb + Es[s] / (4 * nb) + 256;
        pk.s[s].gcur = gcur_all + s * 512;
        pk.s[s].rowptr = (int*)p;   p += ((size_t)(Ns[s] + 1 + 3) & ~(size_t)3) * 4;
        pk.s[s].dis = (float*)p;    p += ((size_t)(Ns[s] + 3) & ~(size_t)3) * 4;
    }
    for (int s = 0; s < 4; s++) {
        pk.s[s].csr = (int*)p;      p += ((size_t)(Es[s] + 3) & ~(size_t)3) * 4;
    }

    // union region: pairs (build phase) aliases g|act|xt (compute phase)
    char* U = p;
    size_t pairsBytes = 0;
    for (int s = 0; s < 4; s++) {
        int nb = cdiv(Ns[s], 1 << pk.s[s].bits);
        pk.s[s].pairs = (u32*)(U + pairsBytes);
        pairsBytes += (size_t)pk.s[s].cap * nb * 4;
    }
    bf16* g   = (bf16*)U;
    bf16* act = g + gmax;
    bf16* xt  = act + amax;

    // grids
    int ptot = 0, btot = 0;
    for (int s = 0; s < 4; s++) {
        pk.poff[s] = ptot; ptot += cdiv(Es[s], TILE);
        pk.boff[s] = btot; btot += cdiv(Ns[s], 1 << pk.s[s].bits);
    }

    const int B = 256;

    k_detect<<<1, 256, 0, stream>>>((const u16*)x, flag);
    k_init<<<8, 256, 0, stream>>>(gcur_all, pk);
    k_partition4<<<ptot, B, 0, stream>>>(pk);
    k_build4<<<btot, B, 0, stream>>>(pk);

    // ---- stage 1 (agg-first): aggregate x (3 feats), then @W1 -> 32
    k_pre<3, true><<<cdiv((long long)N0 * 3, B), B, 0, stream>>>(
        x, nullptr, nullptr, pk.s[0].dis, g, flag, N0 * 3);
    k_gather3e<false><<<cdiv(N0, 256), B, 0, stream>>>(
        g, pk.s[0].rowptr, pk.s[0].csr, pk.s[0].dis, nullptr, xt, flag, N0);
    k_matmul_post<3, 32><<<cdiv(N0, B), B, 0, stream>>>(xt, W1, b1, act, flag, N0);

    // ---- stage 2 (agg-first): aggregate act1[up1] (32 feats), then @W2 -> 64
    k_pre<32, false><<<cdiv((long long)N1 * 32, B), B, 0, stream>>>(
        nullptr, up1, act, pk.s[1].dis, g, flag, N1 * 32);
    k_gather32e<false><<<cdiv(N1, 64), B, 0, stream>>>(
        g, pk.s[1].rowptr, pk.s[1].csr, pk.s[1].dis, nullptr, xt, flag, N1);
    k_matmul_post<32, 64><<<cdiv(N1, B), B, 0, stream>>>(xt, W2, b2, act, flag, N1);

    // ---- stage 3 (W-first): act2[up2] @ W3 -> 32, then aggregate (32 feats)
    k_matmul<64, 32><<<cdiv(N2, B), B, 0, stream>>>(up2, act, W3, pk.s[2].dis, g, flag, N2);
    k_gather32e<true><<<cdiv(N2, 64), B, 0, stream>>>(
        g, pk.s[2].rowptr, pk.s[2].csr, pk.s[2].dis, b3, act, flag, N2);

    // ---- stage 4 (W-first): act3[up3] @ W4 -> 3, then aggregate (3 feats)
    k_matmul<32, 3><<<cdiv(N3, B), B, 0, stream>>>(up3, act, W4, pk.s[3].dis, g, flag, N3);
    k_gather3e<true><<<cdiv(N3, 256), B, 0, stream>>>(
        g, pk.s[3].rowptr, pk.s[3].csr, pk.s[3].dis, b4, act, flag, N3);

    // ---- final unpool
    k_gather_out<<<cdiv(N4, B), B, 0, stream>>>(act, up4, d_out, flag, N4);
}

// Round 2
// 554.656 us; speedup vs baseline: 2.0473x; 2.0473x over previous
//
#include <hip/hip_runtime.h>
#include <hip/hip_bf16.h>

typedef __hip_bfloat16 bf16;
typedef unsigned short u16;
typedef unsigned char u8;
typedef unsigned int u32;
typedef __attribute__((ext_vector_type(8))) unsigned short us8;

static __device__ __forceinline__ float b2f(bf16 v) { return __bfloat162float(v); }
static __device__ __forceinline__ float bfu2f(u16 u) {
    union { u32 i; float f; } c; c.i = ((u32)u) << 16; return c.f;
}
static __device__ __forceinline__ u16 f2bfu(float f) {
    u32 x = __float_as_uint(f);
    return (u16)((x + 0x7FFFu + ((x >> 16) & 1u)) >> 16);
}

#define TILE 4096        // edges per partition block (LDS staging)
#define RPT16(M) M(0) M(1) M(2) M(3) M(4) M(5) M(6) M(7) \
                 M(8) M(9) M(10) M(11) M(12) M(13) M(14) M(15)

struct SP {
    const int* src; const int* dst;
    int E, N, bits, cap;
    int* gcur; u32* pairs;
    int* rowptr; float* dis; int* csr;
};
struct Pack {
    SP s[4];
    int poff[4];  // partition-grid start offset per stage
    int boff[4];  // build-grid start offset per stage
};

// ---------------- dtype detection ----------------
__global__ void k_detect(const u16* __restrict__ xraw, int* __restrict__ flag) {
    __shared__ int s;
    if (threadIdx.x == 0) s = 0;
    __syncthreads();
    u16 u = xraw[threadIdx.x];
    int e = (u >> 7) & 0xFF;
    if (e >= 0x8F) atomicAdd(&s, 1);
    __syncthreads();
    if (threadIdx.x == 0) flag[0] = (s > 0) ? 1 : 0;
}

// zero all 4 gcursor blocks + write rowptr sentinels
__global__ void k_init(int* __restrict__ gcur_all, Pack pk) {
    int i = blockIdx.x * blockDim.x + threadIdx.x;
    if (i < 2048) gcur_all[i] = 0;
    if (i < 4) pk.s[i].rowptr[pk.s[i].N] = pk.s[i].E;
}

// ---------------- fused pass A: all 4 stages' partitions ----------------
// pairs[bucket*cap + slot] = (bucket_local_dst << 20) | src   (src < 2^20)
__global__ void k_partition4(Pack pk) {
    __shared__ u32 stage[TILE];   // 16 KB
    __shared__ u8  bkt[TILE];     //  4 KB
    __shared__ int hist[256];
    __shared__ int lofs[256];
    __shared__ int gbase[256];
    __shared__ int lcur[256];
    __shared__ int tmp[256];

    int bid = blockIdx.x;
    int si = (bid >= pk.poff[3]) ? 3 : (bid >= pk.poff[2]) ? 2 : (bid >= pk.poff[1]) ? 1 : 0;
    const SP sp = pk.s[si];
    int lb = bid - pk.poff[si];

    int t = threadIdx.x;
    int e0 = lb * TILE;
    int n = min(TILE, sp.E - e0);
    int bits = sp.bits;
    const int* dstp = sp.dst + e0;
    const int* srcp = sp.src + e0;

#define LOADK(k) int d##k, s##k; { int i = t + 256*(k); \
    if (i < n) { d##k = dstp[i]; s##k = srcp[i]; } else { d##k = -1; s##k = 0; } }
    RPT16(LOADK)
#undef LOADK

    hist[t] = 0;
    __syncthreads();
#define HISTK(k) if (d##k >= 0) atomicAdd(&hist[d##k >> bits], 1);
    RPT16(HISTK)
#undef HISTK
    __syncthreads();

    int h = hist[t];
    tmp[t] = h; __syncthreads();
    for (int off = 1; off < 256; off <<= 1) {
        int v = (t >= off) ? tmp[t - off] : 0;
        __syncthreads();
        tmp[t] += v;
        __syncthreads();
    }
    lofs[t] = tmp[t] - h;
    gbase[t] = h ? atomicAdd(&sp.gcur[t], h) : 0;
    lcur[t] = tmp[t] - h;
    __syncthreads();

    u32 mask = (1u << bits) - 1u;
#define SCATK(k) if (d##k >= 0) { int b = d##k >> bits; \
    int pos = atomicAdd(&lcur[b], 1); \
    stage[pos] = (((u32)d##k & mask) << 20) | (u32)s##k; \
    bkt[pos] = (u8)b; }
    RPT16(SCATK)
#undef SCATK
    __syncthreads();

    int cap = sp.cap;
    u32* pairs = sp.pairs;
    for (int i = t; i < n; i += 256) {
        int b = bkt[i];
        pairs[(size_t)b * cap + gbase[b] + (i - lofs[b])] = stage[i];
    }
}

// ---------------- fused pass B: all 4 stages' builds ----------------
__global__ void k_build4(Pack pk) {
    __shared__ int hist[4096];   // 16 KB
    __shared__ int ofs[4096];    // 16 KB
    __shared__ int tmp[256];
    __shared__ int bscan[256];

    int bid = blockIdx.x;
    int si = (bid >= pk.boff[3]) ? 3 : (bid >= pk.boff[2]) ? 2 : (bid >= pk.boff[1]) ? 1 : 0;
    const SP sp = pk.s[si];
    int b = bid - pk.boff[si];
    int t = threadIdx.x;
    int bits = sp.bits;
    int range = 1 << bits;

    {
        int v = sp.gcur[t];
        tmp[t] = v; __syncthreads();
        for (int off = 1; off < 256; off <<= 1) {
            int w = (t >= off) ? tmp[t - off] : 0;
            __syncthreads();
            tmp[t] += w;
            __syncthreads();
        }
        bscan[t] = tmp[t] - v;
        __syncthreads();
    }
    int bbase = bscan[b];
    int tot = sp.gcur[b];

    for (int i = t; i < range; i += 256) hist[i] = 0;
    __syncthreads();
    const u32* p = sp.pairs + (size_t)b * sp.cap;
    for (int i = t; i < tot; i += 256)
        atomicAdd(&hist[p[i] >> 20], 1);
    __syncthreads();

    int bpt = range >> 8;  // bins per thread
    int lbase = t * bpt;
    int s = 0;
    for (int k = 0; k < bpt; k++) s += hist[lbase + k];
    tmp[t] = s; __syncthreads();
    for (int off = 1; off < 256; off <<= 1) {
        int v = (t >= off) ? tmp[t - off] : 0;
        __syncthreads();
        tmp[t] += v;
        __syncthreads();
    }
    int run = tmp[t] - s;
    for (int k = 0; k < bpt; k++) { ofs[lbase + k] = run; run += hist[lbase + k]; }
    __syncthreads();

    int nbase = b << bits;
    for (int i = t; i < range; i += 256) {
        int v = nbase + i;
        if (v < sp.N) {
            sp.rowptr[v] = bbase + ofs[i];
            sp.dis[v] = rsqrtf((float)(hist[i] + 1));
        }
    }
    for (int i = t; i < range; i += 256) hist[i] = ofs[i];  // reuse as cursor
    __syncthreads();
    for (int i = t; i < tot; i += 256) {
        u32 u = p[i];
        int pos = atomicAdd(&hist[u >> 20], 1);
        sp.csr[bbase + pos] = (int)(u & 0xFFFFFu);
    }
}

// ---------------- pre-scale: g[v,f] = dis[v] * x_in[row(v), f] ----------------
template <int F, bool EXT>
__global__ void k_pre(const void* __restrict__ xin, const int* __restrict__ gidx,
                      const bf16* __restrict__ actin, const float* __restrict__ dis,
                      bf16* __restrict__ g, const int* __restrict__ flag, int total) {
    int i = blockIdx.x * blockDim.x + threadIdx.x;
    if (i >= total) return;
    int v = i / F;
    int f = i - v * F;
    float x;
    if (EXT) {
        if (flag[0]) x = ((const float*)xin)[i];
        else         x = b2f(((const bf16*)xin)[i]);
    } else {
        int row = gidx[v];
        x = b2f(actin[(size_t)row * F + f]);
    }
    g[i] = __float2bfloat16(dis[v] * x);
}

// ---------------- W-first matmul: g[v,:] = bf16(dis[v] * (act[gidx(v)] @ W)) ----------------
template <int FIN, int FOUT>
__global__ void k_matmul(const int* __restrict__ gidx, const bf16* __restrict__ actin,
                         const void* __restrict__ W, const float* __restrict__ dis,
                         bf16* __restrict__ g, const int* __restrict__ flag, int n) {
    __shared__ float Ws[FIN * FOUT];
    const int f32m = flag[0];
    for (int i = threadIdx.x; i < FIN * FOUT; i += blockDim.x)
        Ws[i] = f32m ? ((const float*)W)[i] : b2f(((const bf16*)W)[i]);
    __syncthreads();
    int v = blockIdx.x * blockDim.x + threadIdx.x;
    if (v >= n) return;
    int row = gidx[v];
    float x[FIN];
    if constexpr (FIN % 8 == 0) {
        #pragma unroll
        for (int k8 = 0; k8 < FIN / 8; k8++) {
            us8 xv = *(const us8*)(actin + (size_t)row * FIN + k8 * 8);
            #pragma unroll
            for (int j = 0; j < 8; j++) x[k8 * 8 + j] = bfu2f(xv[j]);
        }
    } else {
        #pragma unroll
        for (int k = 0; k < FIN; k++) x[k] = b2f(actin[(size_t)row * FIN + k]);
    }
    float y[FOUT];
    #pragma unroll
    for (int f = 0; f < FOUT; f++) y[f] = 0.f;
    #pragma unroll
    for (int k = 0; k < FIN; k++) {
        float xk = x[k];
        #pragma unroll
        for (int f = 0; f < FOUT; f++) y[f] = fmaf(xk, Ws[k * FOUT + f], y[f]);
    }
    float dv = dis[v];
    if constexpr (FOUT % 8 == 0) {
        #pragma unroll
        for (int f8 = 0; f8 < FOUT / 8; f8++) {
            us8 ov;
            #pragma unroll
            for (int j = 0; j < 8; j++) ov[j] = f2bfu(dv * y[f8 * 8 + j]);
            *(us8*)(g + (size_t)v * FOUT + f8 * 8) = ov;
        }
    } else {
        #pragma unroll
        for (int f = 0; f < FOUT; f++)
            g[(size_t)v * FOUT + f] = __float2bfloat16(dv * y[f]);
    }
}

// ---------------- post matmul (agg-first): act = relu(xt @ W + b) ----------------
template <int FIN, int FOUT>
__global__ void k_matmul_post(const bf16* __restrict__ xt, const void* __restrict__ W,
                              const void* __restrict__ bias, bf16* __restrict__ act,
                              const int* __restrict__ flag, int n) {
    __shared__ float Ws[FIN * FOUT];
    __shared__ float Bs[FOUT];
    const int f32m = flag[0];
    for (int i = threadIdx.x; i < FIN * FOUT; i += blockDim.x)
        Ws[i] = f32m ? ((const float*)W)[i] : b2f(((const bf16*)W)[i]);
    for (int i = threadIdx.x; i < FOUT; i += blockDim.x)
        Bs[i] = f32m ? ((const float*)bias)[i] : b2f(((const bf16*)bias)[i]);
    __syncthreads();
    int v = blockIdx.x * blockDim.x + threadIdx.x;
    if (v >= n) return;
    float x[FIN];
    if constexpr (FIN % 8 == 0) {
        #pragma unroll
        for (int k8 = 0; k8 < FIN / 8; k8++) {
            us8 xv = *(const us8*)(xt + (size_t)v * FIN + k8 * 8);
            #pragma unroll
            for (int j = 0; j < 8; j++) x[k8 * 8 + j] = bfu2f(xv[j]);
        }
    } else {
        #pragma unroll
        for (int k = 0; k < FIN; k++) x[k] = b2f(xt[(size_t)v * FIN + k]);
    }
    float y[FOUT];
    #pragma unroll
    for (int f = 0; f < FOUT; f++) y[f] = Bs[f];
    #pragma unroll
    for (int k = 0; k < FIN; k++) {
        float xk = x[k];
        #pragma unroll
        for (int f = 0; f < FOUT; f++) y[f] = fmaf(xk, Ws[k * FOUT + f], y[f]);
    }
    if constexpr (FOUT % 8 == 0) {
        #pragma unroll
        for (int f8 = 0; f8 < FOUT / 8; f8++) {
            us8 ov;
            #pragma unroll
            for (int j = 0; j < 8; j++) {
                float val = y[f8 * 8 + j];
                ov[j] = f2bfu(val > 0.f ? val : 0.f);
            }
            *(us8*)(act + (size_t)v * FOUT + f8 * 8) = ov;
        }
    } else {
        #pragma unroll
        for (int f = 0; f < FOUT; f++)
            act[(size_t)v * FOUT + f] = __float2bfloat16(y[f] > 0.f ? y[f] : 0.f);
    }
}

// ---------------- CSR gather, DUAL-ROW per thread (2x MLP) ----------------
// Thread i handles elements i and i+H (independent rows -> two concurrent
// dependency chains). Batches of 4 per row, lock-step; tail slots clamp to the
// row's last csr entry (L1 hit, no extra HBM) and are masked out of the sum.
template <int FOUT, bool FINALIZE>
__global__ void __launch_bounds__(256) k_gather2(
        const bf16* __restrict__ g, const int* __restrict__ rowptr,
        const int* __restrict__ csr, const float* __restrict__ dis,
        const void* __restrict__ bias, bf16* __restrict__ out,
        const int* __restrict__ flag, int total, int E) {
    int H = (total + 1) >> 1;
    int i = blockIdx.x * blockDim.x + threadIdx.x;
    if (i >= H) return;
    int Em1 = E - 1;
    int e1 = i;
    int e2 = i + H;
    int e2c = (e2 < total) ? e2 : e1;
    int v1 = e1 / FOUT, f1 = e1 - v1 * FOUT;
    int v2 = e2c / FOUT, f2 = e2c - v2 * FOUT;
    float s1 = b2f(g[e1]);    // self-loop terms
    float s2 = b2f(g[e2c]);
    int r1 = rowptr[v1]; int c1 = rowptr[v1 + 1] - r1;
    int r2 = rowptr[v2]; int c2 = rowptr[v2 + 1] - r2;
    int last1 = min(r1 + (c1 > 0 ? c1 - 1 : 0), Em1);
    int last2 = min(r2 + (c2 > 0 ? c2 - 1 : 0), Em1);
    int j1 = 0, j2 = 0;
    while (j1 < c1 || j2 < c2) {
        int i10 = min(r1 + j1 + 0, last1), i11 = min(r1 + j1 + 1, last1);
        int i12 = min(r1 + j1 + 2, last1), i13 = min(r1 + j1 + 3, last1);
        int i20 = min(r2 + j2 + 0, last2), i21 = min(r2 + j2 + 1, last2);
        int i22 = min(r2 + j2 + 2, last2), i23 = min(r2 + j2 + 3, last2);
        int u10 = csr[i10], u11 = csr[i11], u12 = csr[i12], u13 = csr[i13];
        int u20 = csr[i20], u21 = csr[i21], u22 = csr[i22], u23 = csr[i23];
        float a10 = b2f(g[(size_t)u10 * FOUT + f1]);
        float a11 = b2f(g[(size_t)u11 * FOUT + f1]);
        float a12 = b2f(g[(size_t)u12 * FOUT + f1]);
        float a13 = b2f(g[(size_t)u13 * FOUT + f1]);
        float a20 = b2f(g[(size_t)u20 * FOUT + f2]);
        float a21 = b2f(g[(size_t)u21 * FOUT + f2]);
        float a22 = b2f(g[(size_t)u22 * FOUT + f2]);
        float a23 = b2f(g[(size_t)u23 * FOUT + f2]);
        s1 += ((j1 + 0 < c1 ? a10 : 0.f) + (j1 + 1 < c1 ? a11 : 0.f))
            + ((j1 + 2 < c1 ? a12 : 0.f) + (j1 + 3 < c1 ? a13 : 0.f));
        s2 += ((j2 + 0 < c2 ? a20 : 0.f) + (j2 + 1 < c2 ? a21 : 0.f))
            + ((j2 + 2 < c2 ? a22 : 0.f) + (j2 + 3 < c2 ? a23 : 0.f));
        j1 += 4; j2 += 4;
    }
    float dv1 = dis[v1], dv2 = dis[v2];
    float o1, o2;
    if (FINALIZE) {
        float bf1 = flag[0] ? ((const float*)bias)[f1] : b2f(((const bf16*)bias)[f1]);
        float bf2 = flag[0] ? ((const float*)bias)[f2] : b2f(((const bf16*)bias)[f2]);
        o1 = fmaf(dv1, s1, bf1); o1 = o1 > 0.f ? o1 : 0.f;
        o2 = fmaf(dv2, s2, bf2); o2 = o2 > 0.f ? o2 : 0.f;
    } else {
        o1 = dv1 * s1;
        o2 = dv2 * s2;
    }
    out[e1] = __float2bfloat16(o1);
    if (e2 < total) out[e2] = __float2bfloat16(o2);
}

// ---------------- final unpool gather -> out (dtype per flag) ----------------
__global__ void k_gather_out(const bf16* __restrict__ act, const int* __restrict__ idx,
                             void* __restrict__ out, const int* __restrict__ flag, int n) {
    int u = blockIdx.x * blockDim.x + threadIdx.x;
    if (u >= n) return;
    size_t r = (size_t)idx[u];
    float v0 = b2f(act[3 * r + 0]);
    float v1 = b2f(act[3 * r + 1]);
    float v2 = b2f(act[3 * r + 2]);
    if (flag[0]) {
        float* o = (float*)out;
        o[3 * (size_t)u + 0] = v0; o[3 * (size_t)u + 1] = v1; o[3 * (size_t)u + 2] = v2;
    } else {
        bf16* o = (bf16*)out;
        o[3 * (size_t)u + 0] = __float2bfloat16(v0);
        o[3 * (size_t)u + 1] = __float2bfloat16(v1);
        o[3 * (size_t)u + 2] = __float2bfloat16(v2);
    }
}

static inline int cdiv(long long a, long long b) { return (int)((a + b - 1) / b); }

static inline int range_bits_for(int N) {
    int bits = 8;
    while (cdiv(N, 1 << bits) > 256) bits++;
    return bits;
}

extern "C" void kernel_launch(void* const* d_in, const int* in_sizes, int n_in,
                              void* d_out, int out_size, void* d_ws, size_t ws_size,
                              hipStream_t stream) {
    const void* x  = d_in[0];
    const void* W1 = d_in[1]; const void* b1 = d_in[2];
    const void* W2 = d_in[3]; const void* b2 = d_in[4];
    const void* W3 = d_in[5]; const void* b3 = d_in[6];
    const void* W4 = d_in[7]; const void* b4 = d_in[8];
    const int* e0  = (const int*)d_in[9];
    const int* up1 = (const int*)d_in[10];
    const int* e1  = (const int*)d_in[11];
    const int* up2 = (const int*)d_in[12];
    const int* e2  = (const int*)d_in[13];
    const int* up3 = (const int*)d_in[14];
    const int* e3  = (const int*)d_in[15];
    const int* up4 = (const int*)d_in[16];

    const int N0 = in_sizes[0] / 3;
    const int N1 = in_sizes[10];
    const int N2 = in_sizes[12];
    const int N3 = in_sizes[14];
    const int N4 = in_sizes[16];
    const int E0 = in_sizes[9] / 2, E1 = in_sizes[11] / 2;
    const int E2 = in_sizes[13] / 2, E3 = in_sizes[15] / 2;

    int Ns[4] = {N0, N1, N2, N3};
    int Es[4] = {E0, E1, E2, E3};
    const int* srcs[4] = {e0, e1, e2, e3};
    const int* dsts[4] = {e0 + E0, e1 + E1, e2 + E2, e3 + E3};

    // buffer element counts
    size_t gmax = (size_t)N0 * 3;
    if ((size_t)N1 * 32 > gmax) gmax = (size_t)N1 * 32;
    if ((size_t)N2 * 32 > gmax) gmax = (size_t)N2 * 32;
    if ((size_t)N3 * 3  > gmax) gmax = (size_t)N3 * 3;
    size_t amax = (size_t)N0 * 32;
    if ((size_t)N1 * 64 > amax) amax = (size_t)N1 * 64;
    if ((size_t)N2 * 32 > amax) amax = (size_t)N2 * 32;
    if ((size_t)N3 * 3  > amax) amax = (size_t)N3 * 3;
    size_t xmax = (size_t)N0 * 3;
    if ((size_t)N1 * 32 > xmax) xmax = (size_t)N1 * 32;
    gmax = (gmax + 7) & ~(size_t)7;
    amax = (amax + 7) & ~(size_t)7;
    xmax = (xmax + 7) & ~(size_t)7;

    Pack pk;
    char* p = (char*)d_ws;
    int* flag = (int*)p;            p += 256;
    int* gcur_all = (int*)p;        p += 2048 * 4;

    for (int s = 0; s < 4; s++) {
        pk.s[s].src = srcs[s]; pk.s[s].dst = dsts[s];
        pk.s[s].E = Es[s]; pk.s[s].N = Ns[s];
        pk.s[s].bits = range_bits_for(Ns[s]);
        int nb = cdiv(Ns[s], 1 << pk.s[s].bits);
        pk.s[s].cap = Es[s] / nb + Es[s] / (4 * nb) + 256;
        pk.s[s].gcur = gcur_all + s * 512;
        pk.s[s].rowptr = (int*)p;   p += ((size_t)(Ns[s] + 1 + 3) & ~(size_t)3) * 4;
        pk.s[s].dis = (float*)p;    p += ((size_t)(Ns[s] + 3) & ~(size_t)3) * 4;
    }
    for (int s = 0; s < 4; s++) {
        pk.s[s].csr = (int*)p;      p += ((size_t)(Es[s] + 3) & ~(size_t)3) * 4;
    }

    // union region: pairs (build phase) aliases g|act|xt (compute phase)
    char* U = p;
    size_t pairsBytes = 0;
    for (int s = 0; s < 4; s++) {
        int nb = cdiv(Ns[s], 1 << pk.s[s].bits);
        pk.s[s].pairs = (u32*)(U + pairsBytes);
        pairsBytes += (size_t)pk.s[s].cap * nb * 4;
    }
    bf16* g   = (bf16*)U;
    bf16* act = g + gmax;
    bf16* xt  = act + amax;

    // grids
    int ptot = 0, btot = 0;
    for (int s = 0; s < 4; s++) {
        pk.poff[s] = ptot; ptot += cdiv(Es[s], TILE);
        pk.boff[s] = btot; btot += cdiv(Ns[s], 1 << pk.s[s].bits);
    }

    const int B = 256;

    k_detect<<<1, 256, 0, stream>>>((const u16*)x, flag);
    k_init<<<8, 256, 0, stream>>>(gcur_all, pk);
    k_partition4<<<ptot, B, 0, stream>>>(pk);
    k_build4<<<btot, B, 0, stream>>>(pk);

    // ---- stage 1 (agg-first): aggregate x (3 feats), then @W1 -> 32
    {
        int T = N0 * 3, Hh = (T + 1) >> 1;
        k_pre<3, true><<<cdiv(T, B), B, 0, stream>>>(
            x, nullptr, nullptr, pk.s[0].dis, g, flag, T);
        k_gather2<3, false><<<cdiv(Hh, B), B, 0, stream>>>(
            g, pk.s[0].rowptr, pk.s[0].csr, pk.s[0].dis, nullptr, xt, flag, T, E0);
        k_matmul_post<3, 32><<<cdiv(N0, B), B, 0, stream>>>(xt, W1, b1, act, flag, N0);
    }

    // ---- stage 2 (agg-first): aggregate act1[up1] (32 feats), then @W2 -> 64
    {
        int T = N1 * 32, Hh = (T + 1) >> 1;
        k_pre<32, false><<<cdiv(T, B), B, 0, stream>>>(
            nullptr, up1, act, pk.s[1].dis, g, flag, T);
        k_gather2<32, false><<<cdiv(Hh, B), B, 0, stream>>>(
            g, pk.s[1].rowptr, pk.s[1].csr, pk.s[1].dis, nullptr, xt, flag, T, E1);
        k_matmul_post<32, 64><<<cdiv(N1, B), B, 0, stream>>>(xt, W2, b2, act, flag, N1);
    }

    // ---- stage 3 (W-first): act2[up2] @ W3 -> 32, then aggregate (32 feats)
    {
        int T = N2 * 32, Hh = (T + 1) >> 1;
        k_matmul<64, 32><<<cdiv(N2, B), B, 0, stream>>>(up2, act, W3, pk.s[2].dis, g, flag, N2);
        k_gather2<32, true><<<cdiv(Hh, B), B, 0, stream>>>(
            g, pk.s[2].rowptr, pk.s[2].csr, pk.s[2].dis, b3, act, flag, T, E2);
    }

    // ---- stage 4 (W-first): act3[up3] @ W4 -> 3, then aggregate (3 feats)
    {
        int T = N3 * 3, Hh = (T + 1) >> 1;
        k_matmul<32, 3><<<cdiv(N3, B), B, 0, stream>>>(up3, act, W4, pk.s[3].dis, g, flag, N3);
        k_gather2<3, true><<<cdiv(Hh, B), B, 0, stream>>>(
            g, pk.s[3].rowptr, pk.s[3].csr, pk.s[3].dis, b4, act, flag, T, E3);
    }

    // ---- final unpool
    k_gather_out<<<cdiv(N4, B), B, 0, stream>>>(act, up4, d_out, flag, N4);
}